// Round 1
// baseline (72.386 us; speedup 1.0000x reference)
//
#include <hip/hip_runtime.h>

// PrRoIPool2D(16,16) over full 32x32 box per (n,c) plane == fixed separable
// 4-tap resize. N=128, C=512, H1=W1=32, H2=W2=16.
#define H1 32
#define W1 32
#define H2 16
#define W2 16
#define NPLANES (128 * 512)
#define LDS_STRIDE 36  // 144B rows: 16B-aligned float4 stores + bank spread

__device__ __forceinline__ float tri_G(float t) {
    // antiderivative of max(0, 1-|t|), clamped to support
    t = fminf(1.0f, fmaxf(-1.0f, t));
    return (t <= 0.0f) ? 0.5f * (t + 1.0f) * (t + 1.0f)
                       : 0.5f + t - 0.5f * t * t;
}

__global__ __launch_bounds__(256) void prroi_resize_kernel(
    const float* __restrict__ in, float* __restrict__ out) {
    __shared__ float xs[H1 * LDS_STRIDE];

    const int b = blockIdx.x;   // (n,c) plane index
    const int t = threadIdx.x;  // output element within plane

    // ---- cooperative stage: 1024 floats, one float4 per thread ----
    const float4 v =
        reinterpret_cast<const float4*>(in + (size_t)b * (H1 * W1))[t];
    const int lh = t >> 3;         // row   = (t*4)/32
    const int lw = (t & 7) << 2;   // col   = (t*4)%32
    *reinterpret_cast<float4*>(&xs[lh * LDS_STRIDE + lw]) = v;

    // ---- per-thread weights (block-invariant math, ~40 flops) ----
    const float binsz = 31.0f / 16.0f;
    const int i = t >> 4;   // output row bin
    const int j = t & 15;   // output col bin
    const float ey0 = i * binsz, ey1 = ey0 + binsz;
    const float ex0 = j * binsz, ex1 = ex0 + binsz;
    // first grid point with nonzero triangle weight; support < 4 wide
    int h0 = (int)floorf(ey0 - 1.0f) + 1;
    int w0 = (int)floorf(ex0 - 1.0f) + 1;
    h0 = max(0, min(h0, H1 - 4));
    w0 = max(0, min(w0, W1 - 4));

    float wy[4], wx[4];
#pragma unroll
    for (int k = 0; k < 4; ++k) {
        float p = (float)(h0 + k);
        wy[k] = tri_G(ey1 - p) - tri_G(ey0 - p);
        p = (float)(w0 + k);
        wx[k] = tri_G(ex1 - p) - tri_G(ex0 - p);
    }

    __syncthreads();

    // ---- 4x4 patch gather + weighted sum ----
    float acc = 0.0f;
#pragma unroll
    for (int k = 0; k < 4; ++k) {
        const float* row = &xs[(h0 + k) * LDS_STRIDE + w0];
        float s = row[0] * wx[0] + row[1] * wx[1] +
                  row[2] * wx[2] + row[3] * wx[3];
        acc = fmaf(wy[k], s, acc);
    }

    const float inv_area = 1.0f / (binsz * binsz);
    out[(size_t)b * (H2 * W2) + t] = acc * inv_area;
}

extern "C" void kernel_launch(void* const* d_in, const int* in_sizes, int n_in,
                              void* d_out, int out_size, void* d_ws,
                              size_t ws_size, hipStream_t stream) {
    const float* in = (const float*)d_in[0];
    float* out = (float*)d_out;
    prroi_resize_kernel<<<NPLANES, 256, 0, stream>>>(in, out);
}

// Round 2
// 68.814 us; speedup vs baseline: 1.0519x; 1.0519x over previous
//
#include <hip/hip_runtime.h>

// PrRoIPool2D(16,16) over full 32x32 box per (n,c) plane == fixed separable
// 4-tap resize. N=128, C=512, H1=W1=32, H2=W2=16.
// Persistent-block version: 2048 blocks x 32 planes, double-buffered LDS
// (1 barrier/plane), depth-2 register prefetch, weights hoisted.
#define H1 32
#define W1 32
#define NPLANES (128 * 512)
#define PPB 32                       // planes per block
#define NBLK (NPLANES / PPB)         // 2048 blocks = 8/CU on 256 CUs
#define LDS_STRIDE 36  // 144B rows: 16B-aligned float4 stores, conflict-free write

__device__ __forceinline__ float tri_G(float t) {
    // antiderivative of max(0, 1-|t|), clamped to support
    t = fminf(1.0f, fmaxf(-1.0f, t));
    return (t <= 0.0f) ? 0.5f * (t + 1.0f) * (t + 1.0f)
                       : 0.5f + t - 0.5f * t * t;
}

__global__ __launch_bounds__(256) void prroi_resize_kernel(
    const float* __restrict__ in, float* __restrict__ out) {
    __shared__ float xs[2][H1 * LDS_STRIDE];

    const int t = threadIdx.x;
    const int p0 = blockIdx.x * PPB;

    // ---- staging addresses (hoisted) ----
    const int lh = t >> 3;        // row   = (t*4)/32
    const int lw = (t & 7) << 2;  // col   = (t*4)%32
    float* const st0 = &xs[0][lh * LDS_STRIDE + lw];
    float* const st1 = &xs[1][lh * LDS_STRIDE + lw];

    // ---- per-thread weights, computed ONCE per block ----
    const float binsz = 31.0f / 16.0f;
    const int i = t >> 4;  // output row bin
    const int j = t & 15;  // output col bin
    const float ey0 = i * binsz, ey1 = ey0 + binsz;
    const float ex0 = j * binsz, ex1 = ex0 + binsz;
    int h0 = (int)floorf(ey0 - 1.0f) + 1;
    int w0 = (int)floorf(ex0 - 1.0f) + 1;
    h0 = max(0, min(h0, H1 - 4));
    w0 = max(0, min(w0, W1 - 4));

    const float inv_area = 1.0f / (binsz * binsz);
    float wy[4], wx[4];
#pragma unroll
    for (int k = 0; k < 4; ++k) {
        float p = (float)(h0 + k);
        wy[k] = (tri_G(ey1 - p) - tri_G(ey0 - p)) * inv_area;  // fold 1/area
        p = (float)(w0 + k);
        wx[k] = tri_G(ex1 - p) - tri_G(ex0 - p);
    }
    const int roff = h0 * LDS_STRIDE + w0;

    // ---- depth-2 prefetch prologue ----
    const float4* const src = reinterpret_cast<const float4*>(in);
    float4 v0 = src[(size_t)p0 * 256 + t];
    float4 v1 = src[(size_t)min(p0 + 1, NPLANES - 1) * 256 + t];

    size_t oidx = (size_t)p0 * 256 + t;

#pragma unroll 2
    for (int p = 0; p < PPB; ++p) {
        // write current plane to LDS buffer p&1 (disjoint from the buffer
        // still being read by stragglers in iteration p-1 -> 1 barrier/iter)
        float* const buf = (p & 1) ? &xs[1][0] : &xs[0][0];
        *reinterpret_cast<float4*>((p & 1) ? st1 : st0) = v0;
        v0 = v1;
        const int pn = min(p0 + p + 2, NPLANES - 1);  // clamp: deterministic
        v1 = src[(size_t)pn * 256 + t];               // prefetch, 2 iters ahead

        __syncthreads();

        // 4x4 patch gather + separable weighted sum
        float acc = 0.0f;
#pragma unroll
        for (int k = 0; k < 4; ++k) {
            const float* row = buf + roff + k * LDS_STRIDE;
            float s = row[0] * wx[0] + row[1] * wx[1] +
                      row[2] * wx[2] + row[3] * wx[3];
            acc = fmaf(wy[k], s, acc);
        }
        out[oidx] = acc;
        oidx += 256;
    }
}

extern "C" void kernel_launch(void* const* d_in, const int* in_sizes, int n_in,
                              void* d_out, int out_size, void* d_ws,
                              size_t ws_size, hipStream_t stream) {
    const float* in = (const float*)d_in[0];
    float* out = (float*)d_out;
    prroi_resize_kernel<<<NBLK, 256, 0, stream>>>(in, out);
}

// Round 3
// 68.507 us; speedup vs baseline: 1.0566x; 1.0045x over previous
//
#include <hip/hip_runtime.h>

// PrRoIPool2D(16,16) over full 32x32 box per (n,c) plane == fixed separable
// 4-tap resize. N=128, C=512, H1=W1=32, H2=W2=16.
// Persistent blocks (2048 x 32 planes), double-buffered LDS, depth-2 register
// prefetch, ONE raw s_barrier per plane with NO vmcnt drain (the __syncthreads
// version drains the just-issued prefetch -> exposed HBM latency every plane).
#define H1 32
#define W1 32
#define NPLANES (128 * 512)
#define PPB 32                // planes per block
#define NBLK (NPLANES / PPB)  // 2048 blocks = 8/CU on 256 CUs
#define LDS_STRIDE 36         // 144B rows: aligned float4 stores, ~2-way reads

__device__ __forceinline__ float tri_G(float t) {
    // antiderivative of max(0, 1-|t|), clamped to support
    t = fminf(1.0f, fmaxf(-1.0f, t));
    return (t <= 0.0f) ? 0.5f * (t + 1.0f) * (t + 1.0f)
                       : 0.5f + t - 0.5f * t * t;
}

__global__ __launch_bounds__(256) void prroi_resize_kernel(
    const float* __restrict__ in, float* __restrict__ out) {
    __shared__ float xs[2][H1 * LDS_STRIDE];

    const int t = threadIdx.x;
    const int p0 = blockIdx.x * PPB;

    // ---- staging addresses (hoisted) ----
    const int lh = t >> 3;        // row   = (t*4)/32
    const int lw = (t & 7) << 2;  // col   = (t*4)%32
    float* const st0 = &xs[0][lh * LDS_STRIDE + lw];
    float* const st1 = &xs[1][lh * LDS_STRIDE + lw];

    // ---- per-thread weights, computed ONCE per block ----
    const float binsz = 31.0f / 16.0f;
    const int i = t >> 4;  // output row bin
    const int j = t & 15;  // output col bin
    const float ey0 = i * binsz, ey1 = ey0 + binsz;
    const float ex0 = j * binsz, ex1 = ex0 + binsz;
    int h0 = (int)floorf(ey0 - 1.0f) + 1;
    int w0 = (int)floorf(ex0 - 1.0f) + 1;
    h0 = max(0, min(h0, H1 - 4));
    w0 = max(0, min(w0, W1 - 4));

    const float inv_area = 1.0f / (binsz * binsz);
    float wy[4], wx[4];
#pragma unroll
    for (int k = 0; k < 4; ++k) {
        float p = (float)(h0 + k);
        wy[k] = (tri_G(ey1 - p) - tri_G(ey0 - p)) * inv_area;  // fold 1/area
        p = (float)(w0 + k);
        wx[k] = tri_G(ex1 - p) - tri_G(ex0 - p);
    }
    // per-thread read bases (immediate ds offsets cover k*144 + m*4 <= 444B)
    const float* const rp0 = &xs[0][h0 * LDS_STRIDE + w0];
    const float* const rp1 = &xs[1][h0 * LDS_STRIDE + w0];

    // ---- depth-2 prefetch prologue ----
    const float4* const src = reinterpret_cast<const float4*>(in);
    float4 v0 = src[(size_t)p0 * 256 + t];
    float4 v1 = src[(size_t)(p0 + 1) * 256 + t];

    size_t oidx = (size_t)p0 * 256 + t;

#pragma unroll 2
    for (int p = 0; p < PPB; ++p) {
        // stage plane p into buf[p&1]; compiler inserts a counted vmcnt wait
        // for v0 (load issued 2 iterations ago -> fully covered)
        *reinterpret_cast<float4*>((p & 1) ? st1 : st0) = v0;
        v0 = v1;
        const int pn = min(p0 + p + 2, NPLANES - 1);  // clamp: deterministic
        v1 = src[(size_t)pn * 256 + t];               // prefetch, 2 iters ahead

        // my ds_write visible, then raw barrier: NO vmcnt drain, so the
        // prefetch load and prior stores stay in flight across it.
        asm volatile("s_waitcnt lgkmcnt(0)" ::: "memory");
        __builtin_amdgcn_s_barrier();
        __builtin_amdgcn_sched_barrier(0);  // keep ds_reads below the barrier

        // 4x4 patch gather + separable weighted sum
        const float* const base = (p & 1) ? rp1 : rp0;
        float acc = 0.0f;
#pragma unroll
        for (int k = 0; k < 4; ++k) {
            const float* row = base + k * LDS_STRIDE;
            float s = row[0] * wx[0] + row[1] * wx[1] +
                      row[2] * wx[2] + row[3] * wx[3];
            acc = fmaf(wy[k], s, acc);
        }
        out[oidx] = acc;
        oidx += 256;
    }
}

extern "C" void kernel_launch(void* const* d_in, const int* in_sizes, int n_in,
                              void* d_out, int out_size, void* d_ws,
                              size_t ws_size, hipStream_t stream) {
    const float* in = (const float*)d_in[0];
    float* out = (float*)d_out;
    prroi_resize_kernel<<<NBLK, 256, 0, stream>>>(in, out);
}